// Round 5
// baseline (626.259 us; speedup 1.0000x reference)
//
#include <hip/hip_runtime.h>

typedef unsigned short u16;
typedef unsigned int u32;
typedef __attribute__((ext_vector_type(4))) float f32x4;
typedef __attribute__((ext_vector_type(4))) u16 u16x4;
typedef __attribute__((ext_vector_type(8))) u16 u16x8;
typedef __attribute__((ext_vector_type(8))) __bf16 bf16x8;

// Problem dims (fixed by setup_inputs): B=32, S=1024, I=H=1024
#define BDIM 32
#define SDIM 1024
#define HDIM 1024
#define MT (BDIM*SDIM)   // 32768 GEMM rows
#define NT (3*HDIM)      // 3072  GEMM cols
#define KT 1024          // reduction
#define GATE_U16X4 8388608u  // 32*16*256*64 u16x4 units per gate

__device__ __forceinline__ float bf2f(u16 u) {
  u32 x = ((u32)u) << 16;
  return __builtin_bit_cast(float, x);
}
__device__ __forceinline__ u16 f2bf(float f) {
  u32 x = __builtin_bit_cast(u32, f);
  x = x + 0x7fffu + ((x >> 16) & 1u);
  return (u16)(x >> 16);
}

typedef __attribute__((address_space(1))) void gvoid;
typedef __attribute__((address_space(3))) void lvoid;
__device__ __forceinline__ void gload16(const u16* g, u16* l) {
  // wave-uniform LDS base; HW adds lane*16 on the LDS side; global src is per-lane
  __builtin_amdgcn_global_load_lds((gvoid*)g, (lvoid*)l, 16, 0, 0);
}

// ---------------- cast f32 -> bf16, vectorized (16B in / 8B out per lane) ---
__global__ void cast_kernel(const float* __restrict__ in, u16* __restrict__ out, int n4) {
  int idx = blockIdx.x * blockDim.x + threadIdx.x;
  int stride = gridDim.x * blockDim.x;
  const f32x4* in4 = (const f32x4*)in;
  u16x4* out4 = (u16x4*)out;
  for (int i = idx; i < n4; i += stride) {
    f32x4 v = in4[i];
    u16x4 o;
    o[0] = f2bf(v[0]); o[1] = f2bf(v[1]); o[2] = f2bf(v[2]); o[3] = f2bf(v[3]);
    out4[i] = o;
  }
}

// ---------------- bf16 GEMM: C[m][n] = sum_k A[m][k]*W[n][k] + bias[n] ------
// m97 structure: 128x128 tile, BK=32, 4 waves (2x2), global_load_lds width=16.
// Epilogue writes transposed-tiled layout T[g][b][hg][t4][hl] : u16x4 over v,
// where t = t4*4 + v, so the scan reads 4 consecutive timesteps per dwordx2.
__global__ __launch_bounds__(256) void gemm_kernel(
    const u16* __restrict__ A,     // MT x KT bf16 (x)
    const u16* __restrict__ W,     // NT x KT bf16 (w)
    const float* __restrict__ bias,// NT
    u16x4* __restrict__ CT)        // transposed-tiled wx, 3 gates
{
  __shared__ u16 As[128 * 32];
  __shared__ u16 Bs[128 * 32];
  const int tid  = threadIdx.x;
  const int lane = tid & 63;
  const int wave = tid >> 6;

  // XCD-aware bijective swizzle: grid 6144 = 8 * 768
  int bid = blockIdx.x;
  bid = (bid & 7) * 768 + (bid >> 3);
  const int bm = bid / (NT / 128);
  const int bn = bid % (NT / 128);
  const int wm = (wave >> 1) * 64;   // wave's 64x64 sub-tile
  const int wn = (wave & 1) * 64;

  f32x4 acc[4][4] = {};

  // staging decomposition: 8 chunks of 1KB (16 rows x 32 cols bf16); 2 chunks/wave
  const int rsub = lane >> 2;         // 0..15
  const int ksub = (lane & 3) * 8;    // 0,8,16,24
  const int c0 = wave * 2;

  const u16* Ab0 = A + (size_t)(bm * 128 + c0 * 16 + rsub) * KT + ksub;
  const u16* Ab1 = A + (size_t)(bm * 128 + (c0 + 1) * 16 + rsub) * KT + ksub;
  const u16* Wb0 = W + (size_t)(bn * 128 + c0 * 16 + rsub) * KT + ksub;
  const u16* Wb1 = W + (size_t)(bn * 128 + (c0 + 1) * 16 + rsub) * KT + ksub;
  u16* lA0 = &As[c0 * 512];
  u16* lA1 = &As[(c0 + 1) * 512];
  u16* lB0 = &Bs[c0 * 512];
  u16* lB1 = &Bs[(c0 + 1) * 512];

  const int fr = lane & 15;           // fragment row (A) / col (B)
  const int fk = (lane >> 4) * 8;     // fragment k offset

  for (int kt = 0; kt < KT / 32; ++kt) {
    const int k0 = kt * 32;
    gload16(Ab0 + k0, lA0);
    gload16(Ab1 + k0, lA1);
    gload16(Wb0 + k0, lB0);
    gload16(Wb1 + k0, lB1);
    __syncthreads();   // compiler emits vmcnt(0) drain before s_barrier

    bf16x8 av[4], bv[4];
#pragma unroll
    for (int mi = 0; mi < 4; ++mi)
      av[mi] = *(const bf16x8*)&As[(wm + mi * 16 + fr) * 32 + fk];
#pragma unroll
    for (int ni = 0; ni < 4; ++ni)
      bv[ni] = *(const bf16x8*)&Bs[(wn + ni * 16 + fr) * 32 + fk];
#pragma unroll
    for (int mi = 0; mi < 4; ++mi)
#pragma unroll
      for (int ni = 0; ni < 4; ++ni)
        acc[mi][ni] = __builtin_amdgcn_mfma_f32_16x16x32_bf16(av[mi], bv[ni], acc[mi][ni], 0, 0, 0);
    __syncthreads();
  }

  // epilogue: C/D layout col = lane&15, row = (lane>>4)*4 + reg  [m89-verified]
  // 128-row tile lies in one b (bm&7 selects sub-block); 128-col tile in one gate.
  const int b_i   = bm >> 3;
  const int trow  = ((bm & 7) << 7) + wm + ((lane >> 4) << 2);
  const int g     = bn >> 3;
  const int hbase = ((bn & 7) << 7) + wn + (lane & 15);
  u16x4* Tg = CT + (size_t)g * GATE_U16X4;

#pragma unroll
  for (int ni = 0; ni < 4; ++ni) {
    const int h  = hbase + ni * 16;
    const int hg = h >> 6;
    const int hl = h & 63;
    const float bb = bias[g * 1024 + h];
#pragma unroll
    for (int mi = 0; mi < 4; ++mi) {
      const int t4 = (trow + mi * 16) >> 2;
      u16x4 o;
#pragma unroll
      for (int v = 0; v < 4; ++v) o[v] = f2bf(acc[mi][ni][v] + bb);
      Tg[((size_t)(b_i * 16 + hg) * 256 + t4) * 64 + hl] = o;
    }
  }
}

// ---------------- fused scan + output, register double-buffered --------------
// One wave per block; 512 blocks; lane owns one (b,h) chain. Per 16-t chunk:
// 12 dwordx2 (wf/wc/wr, 4 steps each) + 16 dword (x f32) independent loads,
// staged depth-2 via 4 named register buffers (no LDS, no barriers).
struct Buf {
  u16x4 f[4], w[4], r[4];
  float x[16];
};

__global__ __launch_bounds__(64) void scan_kernel(
    const u16x4* __restrict__ CT,  // transposed-tiled wx
    const float* __restrict__ x,   // (B*S) x H f32
    const float* __restrict__ vf,
    const float* __restrict__ vr,
    float* __restrict__ h_out,     // (B*S) x H f32
    float* __restrict__ c_last)    // B x H f32
{
  const int lane = threadIdx.x;
  const int bid  = blockIdx.x;          // 0..511
  const int b    = bid >> 4;            // 0..31
  const int hg   = bid & 15;
  const int h    = (hg << 6) + lane;    // 0..1023

  const float vfh = vf[h];
  const float vrh = vr[h];
  const float SC = 1.7320508075688772f; // sqrt(3)

  const u16x4* Tf = CT + (size_t)(b * 16 + hg) * 256 * 64 + lane;
  const u16x4* Tw = Tf + GATE_U16X4;
  const u16x4* Tr = Tf + 2 * (size_t)GATE_U16X4;
  const float* px = x + (size_t)(b * SDIM) * HDIM + h;
  float* ph = h_out + (size_t)(b * SDIM) * HDIM + h;

  auto LOAD = [&](Buf& bf, int kc) {
#pragma unroll
    for (int j = 0; j < 4; ++j) {
      const size_t o = (size_t)(kc * 4 + j) * 64;
      bf.f[j] = Tf[o];
      bf.w[j] = Tw[o];
      bf.r[j] = Tr[o];
    }
#pragma unroll
    for (int r = 0; r < 16; ++r)
      bf.x[r] = px[(size_t)(kc * 16 + r) * HDIM];
  };

  float c = 0.0f;

  auto COMPUTE = [&](const Buf& bf, int k) {
#pragma unroll
    for (int r = 0; r < 16; ++r) {
      const float wf = bf2f(bf.f[r >> 2][r & 3]);
      const float wc = bf2f(bf.w[r >> 2][r & 3]);
      const float wr = bf2f(bf.r[r >> 2][r & 3]);
      const float xv = bf.x[r];

      const float ef = __expf(-(wf + vfh * c));
      const float fg = 1.0f / (1.0f + ef);
      const float cn = fg * (c - wc) + wc;

      const float er = __expf(-(wr + vrh * c));   // uses prev c
      const float rr = 1.0f / (1.0f + er);

      const float xs = xv * SC;
      ph[(size_t)(k * 16 + r) * HDIM] = rr * (cn - xs) + xs;
      c = cn;
    }
  };

  Buf A0, A1, B0, B1;
  LOAD(A0, 0); LOAD(A1, 1);
  for (int k = 0; k < 64; k += 4) {
    LOAD(B0, (k + 2 < 64) ? k + 2 : 63);
    COMPUTE(A0, k);
    LOAD(B1, (k + 3 < 64) ? k + 3 : 63);
    COMPUTE(A1, k + 1);
    LOAD(A0, (k + 4 < 64) ? k + 4 : 63);
    COMPUTE(B0, k + 2);
    LOAD(A1, (k + 5 < 64) ? k + 5 : 63);
    COMPUTE(B1, k + 3);
  }

  c_last[(size_t)b * HDIM + h] = c;
}

extern "C" void kernel_launch(void* const* d_in, const int* in_sizes, int n_in,
                              void* d_out, int out_size, void* d_ws, size_t ws_size,
                              hipStream_t stream) {
  const float* x  = (const float*)d_in[0];   // 32*1024*1024
  const float* w  = (const float*)d_in[1];   // 3072*1024
  const float* b  = (const float*)d_in[2];   // 3072
  const float* vf = (const float*)d_in[3];   // 1024
  const float* vr = (const float*)d_in[4];   // 1024

  float* out    = (float*)d_out;
  float* h_out  = out;                       // 33554432 f32
  float* c_last = out + (size_t)33554432;    // 32768 f32

  char* ws = (char*)d_ws;
  u16* xb = (u16*)ws;                               // 67108864 B
  u16* wb = (u16*)(ws + 67108864);                  // 6291456 B
  u16x4* wxT = (u16x4*)(ws + 67108864 + 6291456);   // 201326592 B (3 gates)

  cast_kernel<<<4096, 256, 0, stream>>>(x, xb, (int)(33554432 / 4));
  cast_kernel<<<1024, 256, 0, stream>>>(w, wb, (int)(3145728 / 4));
  gemm_kernel<<<(MT / 128) * (NT / 128), 256, 0, stream>>>(xb, wb, b, wxT);
  scan_kernel<<<512, 64, 0, stream>>>(wxT, x, vf, vr, h_out, c_last);
}

// Round 10
// 612.647 us; speedup vs baseline: 1.0222x; 1.0222x over previous
//
#include <hip/hip_runtime.h>

typedef unsigned short u16;
typedef unsigned int u32;
typedef __attribute__((ext_vector_type(4))) float f32x4;
typedef __attribute__((ext_vector_type(4))) u16 u16x4;
typedef __attribute__((ext_vector_type(8))) u16 u16x8;
typedef __attribute__((ext_vector_type(8))) __bf16 bf16x8;

// Problem dims (fixed by setup_inputs): B=32, S=1024, I=H=1024
#define BDIM 32
#define SDIM 1024
#define HDIM 1024
#define MT (BDIM*SDIM)   // 32768 GEMM rows
#define NT (3*HDIM)      // 3072  GEMM cols
#define KT 1024          // reduction
#define TILE_U (8388608u)  // 32*16*256*64 tiled units (per gate)

__device__ __forceinline__ float bf2f(u16 u) {
  u32 x = ((u32)u) << 16;
  return __builtin_bit_cast(float, x);
}
__device__ __forceinline__ u16 f2bf(float f) {
  u32 x = __builtin_bit_cast(u32, f);
  x = x + 0x7fffu + ((x >> 16) & 1u);
  return (u16)(x >> 16);
}

typedef __attribute__((address_space(1))) void gvoid;
typedef __attribute__((address_space(3))) void lvoid;
__device__ __forceinline__ void gload16(const u16* g, u16* l) {
  __builtin_amdgcn_global_load_lds((gvoid*)g, (lvoid*)l, 16, 0, 0);
}

// ---------------- cast f32 -> bf16 ------------------------------------------
__global__ void cast_kernel(const float* __restrict__ in, u16* __restrict__ out, int n4) {
  int idx = blockIdx.x * blockDim.x + threadIdx.x;
  int stride = gridDim.x * blockDim.x;
  const f32x4* in4 = (const f32x4*)in;
  u16x4* out4 = (u16x4*)out;
  for (int i = idx; i < n4; i += stride) {
    f32x4 v = in4[i];
    u16x4 o;
    o[0] = f2bf(v[0]); o[1] = f2bf(v[1]); o[2] = f2bf(v[2]); o[3] = f2bf(v[3]);
    out4[i] = o;
  }
}

// ---------------- bf16 GEMM -------------------------------------------------
// C[m][n] = sum_k A[m][k]*W[n][k] + bias[n].  m97 structure: 128x128 tile,
// BK=32, 4 waves, global_load_lds width=16.
// Epilogue (tiled layout, validated round 5):
//   idx = ((b*16+hg)*256 + t4)*64 + hl,  t = t4*4 + v (v = C/D reg index)
//   gate 0 (wf) -> PW[idx*2+0], gate 1 (wc) -> PW[idx*2+1]  (scan1: 1 dwordx4)
//   gate 2 (wr) -> R[idx]                                   (scan2 operand)
__global__ __launch_bounds__(256) void gemm_kernel(
    const u16* __restrict__ A,     // MT x KT bf16 (x)
    const u16* __restrict__ W,     // NT x KT bf16 (w)
    const float* __restrict__ bias,// NT
    u16x4* __restrict__ PW,        // interleaved {f4,w4}: 2*TILE_U u16x4 units
    u16x4* __restrict__ R)         // wr tiled: TILE_U units
{
  __shared__ u16 As[128 * 32];
  __shared__ u16 Bs[128 * 32];
  const int tid  = threadIdx.x;
  const int lane = tid & 63;
  const int wave = tid >> 6;

  // XCD-aware bijective swizzle: grid 6144 = 8 * 768
  int bid = blockIdx.x;
  bid = (bid & 7) * 768 + (bid >> 3);
  const int bm = bid / (NT / 128);
  const int bn = bid % (NT / 128);
  const int wm = (wave >> 1) * 64;
  const int wn = (wave & 1) * 64;

  f32x4 acc[4][4] = {};

  const int rsub = lane >> 2;
  const int ksub = (lane & 3) * 8;
  const int c0 = wave * 2;

  const u16* Ab0 = A + (size_t)(bm * 128 + c0 * 16 + rsub) * KT + ksub;
  const u16* Ab1 = A + (size_t)(bm * 128 + (c0 + 1) * 16 + rsub) * KT + ksub;
  const u16* Wb0 = W + (size_t)(bn * 128 + c0 * 16 + rsub) * KT + ksub;
  const u16* Wb1 = W + (size_t)(bn * 128 + (c0 + 1) * 16 + rsub) * KT + ksub;
  u16* lA0 = &As[c0 * 512];
  u16* lA1 = &As[(c0 + 1) * 512];
  u16* lB0 = &Bs[c0 * 512];
  u16* lB1 = &Bs[(c0 + 1) * 512];

  const int fr = lane & 15;
  const int fk = (lane >> 4) * 8;

  for (int kt = 0; kt < KT / 32; ++kt) {
    const int k0 = kt * 32;
    gload16(Ab0 + k0, lA0);
    gload16(Ab1 + k0, lA1);
    gload16(Wb0 + k0, lB0);
    gload16(Wb1 + k0, lB1);
    __syncthreads();

    bf16x8 av[4], bv[4];
#pragma unroll
    for (int mi = 0; mi < 4; ++mi)
      av[mi] = *(const bf16x8*)&As[(wm + mi * 16 + fr) * 32 + fk];
#pragma unroll
    for (int ni = 0; ni < 4; ++ni)
      bv[ni] = *(const bf16x8*)&Bs[(wn + ni * 16 + fr) * 32 + fk];
#pragma unroll
    for (int mi = 0; mi < 4; ++mi)
#pragma unroll
      for (int ni = 0; ni < 4; ++ni)
        acc[mi][ni] = __builtin_amdgcn_mfma_f32_16x16x32_bf16(av[mi], bv[ni], acc[mi][ni], 0, 0, 0);
    __syncthreads();
  }

  // epilogue: C/D layout col = lane&15, row = (lane>>4)*4 + reg  [m89-verified]
  const int b_i   = bm >> 3;
  const int trow  = ((bm & 7) << 7) + wm + ((lane >> 4) << 2);
  const int g     = bn >> 3;                     // gate 0/1/2 (uniform per block)
  const int hbase = ((bn & 7) << 7) + wn + (lane & 15);

#pragma unroll
  for (int ni = 0; ni < 4; ++ni) {
    const int h  = hbase + ni * 16;
    const int hg = h >> 6;
    const int hl = h & 63;
    const float bb = bias[g * 1024 + h];
#pragma unroll
    for (int mi = 0; mi < 4; ++mi) {
      const int t4 = (trow + mi * 16) >> 2;
      const size_t idx = ((size_t)(b_i * 16 + hg) * 256 + t4) * 64 + hl;
      u16x4 o;
#pragma unroll
      for (int v = 0; v < 4; ++v) o[v] = f2bf(acc[mi][ni][v] + bb);
      if (g < 2) PW[idx * 2 + g] = o;
      else       R[idx] = o;
    }
  }
}

// ---------------- scan1: sequential c recurrence ----------------------------
// lane = one (b,h) chain. Per 4 steps: ONE dwordx4 load {wf4,wc4}, 4-step
// chain, one 8B store of packed c. Ring of 8 (32 steps of prefetch ~1000cy
// >= HBM latency). Prefetch index clamped: all accesses strictly in-bounds.
__global__ __launch_bounds__(64) void scan1_kernel(
    const u16x8* __restrict__ PW,  // {f4,w4} 16B units, tiled
    const float* __restrict__ vf,
    u16x4* __restrict__ Cc,        // c bf16, tiled (TILE_U units)
    float* __restrict__ c_last)    // B x H f32
{
  const int lane = threadIdx.x;
  const int bhg  = blockIdx.x;          // b*16+hg, 0..511
  const int b    = bhg >> 4;
  const int h    = ((bhg & 15) << 6) + lane;

  const float vfh = vf[h];
  const u16x8* base = PW + (size_t)bhg * 256 * 64 + lane;
  u16x4* cw = Cc + (size_t)bhg * 256 * 64 + lane;

  u16x8 ring[8];
#pragma unroll
  for (int j = 0; j < 8; ++j) ring[j] = base[(size_t)j * 64];

  float c = 0.0f;
#pragma unroll 8
  for (int g = 0; g < 256; ++g) {
    const u16x8 cur = ring[g & 7];             // static after unroll-8
    const int gp = (g + 8 < 256) ? (g + 8) : 255;   // clamped: in-bounds
    ring[g & 7] = base[(size_t)gp * 64];       // prefetch ~8 groups ahead
    u16x4 oc;
#pragma unroll
    for (int v = 0; v < 4; ++v) {
      const float wf = bf2f(cur[v]);
      const float wc = bf2f(cur[4 + v]);
      const float ef = __expf(-(wf + vfh * c));
      const float f  = 1.0f / (1.0f + ef);
      c = f * (c - wc) + wc;
      oc[v] = f2bf(c);
    }
    cw[(size_t)g * 64] = oc;
  }
  c_last[(size_t)b * HDIM + h] = c;
}

// ---------------- scan2: parallel r-gate + output ---------------------------
// 32768 blocks x 256 threads; block = (bhg, quarter q=blk&63); wave w of the
// block handles t4 = q*4 + w; lane = hl. All (bhg,t4) covered exactly once.
__global__ __launch_bounds__(256) void scan2_kernel(
    const u16x4* __restrict__ R,   // wr tiled
    const u16x4* __restrict__ Cc,  // c bf16 tiled
    const float* __restrict__ x,   // (B*S) x H f32
    const float* __restrict__ vr,
    float* __restrict__ h_out)     // (B*S) x H f32
{
  const int tid = threadIdx.x;
  const int blk = blockIdx.x;           // 0..32767
  const int bhg = blk >> 6;             // 0..511  (FIXED: was blk>>2, OOB!)
  const int t4  = ((blk & 63) << 2) + (tid >> 6);  // 0..255 (FIXED)
  const int hl  = tid & 63;
  const int b   = bhg >> 4;
  const int h   = ((bhg & 15) << 6) + hl;

  const size_t idx = ((size_t)bhg * 256 + t4) * 64 + hl;
  const u16x4 r4 = R[idx];
  const u16x4 c4 = Cc[idx];
  // clamp the prev-c address so a speculated load can't go below the buffer
  const size_t idxp = (t4 == 0) ? idx : idx - 64;
  const float cprev = (t4 == 0) ? 0.0f : bf2f(Cc[idxp][3]);
  const float vrh = vr[h];
  const float SC = 1.7320508075688772f; // sqrt(3)

  const float* px = x + ((size_t)b * SDIM + t4 * 4) * HDIM + h;
  float* ph = h_out + ((size_t)b * SDIM + t4 * 4) * HDIM + h;

#pragma unroll
  for (int v = 0; v < 4; ++v) {
    const float cp = (v == 0) ? cprev : bf2f(c4[v - 1]);
    const float er = __expf(-(bf2f(r4[v]) + vrh * cp));
    const float rr = 1.0f / (1.0f + er);
    const float xs = px[(size_t)v * HDIM] * SC;
    ph[(size_t)v * HDIM] = rr * (bf2f(c4[v]) - xs) + xs;
  }
}

extern "C" void kernel_launch(void* const* d_in, const int* in_sizes, int n_in,
                              void* d_out, int out_size, void* d_ws, size_t ws_size,
                              hipStream_t stream) {
  const float* x  = (const float*)d_in[0];
  const float* w  = (const float*)d_in[1];
  const float* b  = (const float*)d_in[2];
  const float* vf = (const float*)d_in[3];
  const float* vr = (const float*)d_in[4];

  float* out    = (float*)d_out;
  float* h_out  = out;                       // 33554432 f32
  float* c_last = out + (size_t)33554432;    // 32768 f32

  // workspace: xb[64MB] (later aliased by Cc) | wb[6MB] | PW[128MB] | R[64MB]
  char* ws = (char*)d_ws;
  u16*   xb = (u16*)ws;
  u16*   wb = (u16*)(ws + 67108864);
  u16x4* PW = (u16x4*)(ws + 73400320);
  u16x4* R  = (u16x4*)(ws + 73400320 + 134217728);
  u16x4* Cc = (u16x4*)ws;                    // aliases xb (dead after gemm)

  cast_kernel<<<4096, 256, 0, stream>>>(x, xb, 8388608);
  cast_kernel<<<1024, 256, 0, stream>>>(w, wb, 786432);
  gemm_kernel<<<(MT / 128) * (NT / 128), 256, 0, stream>>>(xb, wb, b, PW, R);
  scan1_kernel<<<512, 64, 0, stream>>>((const u16x8*)PW, vf, Cc, c_last);
  scan2_kernel<<<32768, 256, 0, stream>>>(R, Cc, x, vr, h_out);
}

// Round 13
// 611.871 us; speedup vs baseline: 1.0235x; 1.0013x over previous
//
#include <hip/hip_runtime.h>

typedef unsigned short u16;
typedef unsigned int u32;
typedef __attribute__((ext_vector_type(4))) float f32x4;
typedef __attribute__((ext_vector_type(4))) u16 u16x4;
typedef __attribute__((ext_vector_type(8))) u16 u16x8;
typedef __attribute__((ext_vector_type(8))) __bf16 bf16x8;

// Problem dims (fixed by setup_inputs): B=32, S=1024, I=H=1024
#define BDIM 32
#define SDIM 1024
#define HDIM 1024
#define MT (BDIM*SDIM)   // 32768 GEMM rows
#define NT (3*HDIM)      // 3072  GEMM cols
#define KT 1024          // reduction
#define TILE_U (8388608u)  // 32*16*256*64 tiled units (per gate)

__device__ __forceinline__ float bf2f(u16 u) {
  u32 x = ((u32)u) << 16;
  return __builtin_bit_cast(float, x);
}
__device__ __forceinline__ u16 f2bf(float f) {
  u32 x = __builtin_bit_cast(u32, f);
  x = x + 0x7fffu + ((x >> 16) & 1u);
  return (u16)(x >> 16);
}

typedef __attribute__((address_space(1))) void gvoid;
typedef __attribute__((address_space(3))) void lvoid;
__device__ __forceinline__ void gload16(const u16* g, u16* l) {
  // wave-uniform LDS base; HW adds lane*16 on the LDS side; global src is per-lane
  __builtin_amdgcn_global_load_lds((gvoid*)g, (lvoid*)l, 16, 0, 0);
}

// ---------------- cast f32 -> bf16 ------------------------------------------
__global__ void cast_kernel(const float* __restrict__ in, u16* __restrict__ out, int n4) {
  int idx = blockIdx.x * blockDim.x + threadIdx.x;
  int stride = gridDim.x * blockDim.x;
  const f32x4* in4 = (const f32x4*)in;
  u16x4* out4 = (u16x4*)out;
  for (int i = idx; i < n4; i += stride) {
    f32x4 v = in4[i];
    u16x4 o;
    o[0] = f2bf(v[0]); o[1] = f2bf(v[1]); o[2] = f2bf(v[2]); o[3] = f2bf(v[3]);
    out4[i] = o;
  }
}

// ---------------- bf16 GEMM -------------------------------------------------
// C[m][n] = sum_k A[m][k]*W[n][k] + bias[n].  m97 structure: 128x128 tile,
// BK=32, 4 waves, global_load_lds width=16.
// Epilogue (tiled layout, validated round 5):
//   idx = ((b*16+hg)*256 + t4)*64 + hl,  t = t4*4 + v (v = C/D reg index)
//   gate 0 (wf) -> PW[idx*2+0], gate 1 (wc) -> PW[idx*2+1]  (scan1: 1 dwordx4)
//   gate 2 (wr) -> R[idx]                                   (scan2 operand)
__global__ __launch_bounds__(256) void gemm_kernel(
    const u16* __restrict__ A,     // MT x KT bf16 (x)
    const u16* __restrict__ W,     // NT x KT bf16 (w)
    const float* __restrict__ bias,// NT
    u16x4* __restrict__ PW,        // interleaved {f4,w4}: 2*TILE_U u16x4 units
    u16x4* __restrict__ R)         // wr tiled: TILE_U units
{
  __shared__ u16 As[128 * 32];
  __shared__ u16 Bs[128 * 32];
  const int tid  = threadIdx.x;
  const int lane = tid & 63;
  const int wave = tid >> 6;

  // XCD-aware bijective swizzle: grid 6144 = 8 * 768
  int bid = blockIdx.x;
  bid = (bid & 7) * 768 + (bid >> 3);
  const int bm = bid / (NT / 128);
  const int bn = bid % (NT / 128);
  const int wm = (wave >> 1) * 64;
  const int wn = (wave & 1) * 64;

  f32x4 acc[4][4] = {};

  const int rsub = lane >> 2;
  const int ksub = (lane & 3) * 8;
  const int c0 = wave * 2;

  const u16* Ab0 = A + (size_t)(bm * 128 + c0 * 16 + rsub) * KT + ksub;
  const u16* Ab1 = A + (size_t)(bm * 128 + (c0 + 1) * 16 + rsub) * KT + ksub;
  const u16* Wb0 = W + (size_t)(bn * 128 + c0 * 16 + rsub) * KT + ksub;
  const u16* Wb1 = W + (size_t)(bn * 128 + (c0 + 1) * 16 + rsub) * KT + ksub;
  u16* lA0 = &As[c0 * 512];
  u16* lA1 = &As[(c0 + 1) * 512];
  u16* lB0 = &Bs[c0 * 512];
  u16* lB1 = &Bs[(c0 + 1) * 512];

  const int fr = lane & 15;
  const int fk = (lane >> 4) * 8;

  for (int kt = 0; kt < KT / 32; ++kt) {
    const int k0 = kt * 32;
    gload16(Ab0 + k0, lA0);
    gload16(Ab1 + k0, lA1);
    gload16(Wb0 + k0, lB0);
    gload16(Wb1 + k0, lB1);
    __syncthreads();

    bf16x8 av[4], bv[4];
#pragma unroll
    for (int mi = 0; mi < 4; ++mi)
      av[mi] = *(const bf16x8*)&As[(wm + mi * 16 + fr) * 32 + fk];
#pragma unroll
    for (int ni = 0; ni < 4; ++ni)
      bv[ni] = *(const bf16x8*)&Bs[(wn + ni * 16 + fr) * 32 + fk];
#pragma unroll
    for (int mi = 0; mi < 4; ++mi)
#pragma unroll
      for (int ni = 0; ni < 4; ++ni)
        acc[mi][ni] = __builtin_amdgcn_mfma_f32_16x16x32_bf16(av[mi], bv[ni], acc[mi][ni], 0, 0, 0);
    __syncthreads();
  }

  // epilogue: C/D layout col = lane&15, row = (lane>>4)*4 + reg  [m89-verified]
  const int b_i   = bm >> 3;
  const int trow  = ((bm & 7) << 7) + wm + ((lane >> 4) << 2);
  const int g     = bn >> 3;                     // gate 0/1/2 (uniform per block)
  const int hbase = ((bn & 7) << 7) + wn + (lane & 15);

#pragma unroll
  for (int ni = 0; ni < 4; ++ni) {
    const int h  = hbase + ni * 16;
    const int hg = h >> 6;
    const int hl = h & 63;
    const float bb = bias[g * 1024 + h];
#pragma unroll
    for (int mi = 0; mi < 4; ++mi) {
      const int t4 = (trow + mi * 16) >> 2;
      const size_t idx = ((size_t)(b_i * 16 + hg) * 256 + t4) * 64 + hl;
      u16x4 o;
#pragma unroll
      for (int v = 0; v < 4; ++v) o[v] = f2bf(acc[mi][ni][v] + bb);
      if (g < 2) PW[idx * 2 + g] = o;
      else       R[idx] = o;
    }
  }
}

// ---------------- scan1: sequential c recurrence, producer-consumer LDS -----
// One block (4 waves) per bhg tile; 512 blocks (2/CU). Window = 16 groups
// (64 timesteps) = 16KB LDS, double-buffered (32KB). Per window: every wave
// issues 4 global_load_lds (1KB each) into the NEXT buffer while wave 0
// computes the CURRENT window's 64 chain steps from LDS; one barrier/window.
// Stage latency (~1100cy) < compute window (~1800cy) => latency hidden.
__global__ __launch_bounds__(256) void scan1_kernel(
    const u16* __restrict__ PW,    // {f4,w4} 16B units, tiled (as u16)
    const float* __restrict__ vf,
    u16x4* __restrict__ Cc,        // c bf16, tiled (TILE_U units)
    float* __restrict__ c_last)    // B x H f32
{
  __shared__ u16 sbuf[2][16 * 512];     // 2 x 16KB
  const int tid  = threadIdx.x;
  const int lane = tid & 63;
  const int wave = tid >> 6;
  const int bhg  = blockIdx.x;          // 0..511
  const int b    = bhg >> 4;
  const int h    = ((bhg & 15) << 6) + lane;

  const u16* gsrc = PW + (size_t)bhg * 131072;  // 256 groups * 512 u16

  // prologue: stage window 0 (groups 0..15; wave w -> groups w*4..w*4+3)
#pragma unroll
  for (int j = 0; j < 4; ++j) {
    const int g = wave * 4 + j;
    gload16(gsrc + (size_t)g * 512 + lane * 8, &sbuf[0][g * 512]);
  }
  __syncthreads();

  const float vfh = vf[h];
  u16x4* cw = Cc + (size_t)bhg * 16384 + lane;
  float c = 0.0f;

  for (int wnd = 0; wnd < 16; ++wnd) {
    // stage next window into the other buffer
    if (wnd + 1 < 16) {
      const int nbuf = (wnd + 1) & 1;
#pragma unroll
      for (int j = 0; j < 4; ++j) {
        const int gl = wave * 4 + j;                 // 0..15 within window
        const int g  = (wnd + 1) * 16 + gl;          // global group
        gload16(gsrc + (size_t)g * 512 + lane * 8, &sbuf[nbuf][gl * 512]);
      }
    }
    // wave 0 computes current window (64 steps)
    if (wave == 0) {
      const int cbuf = wnd & 1;
#pragma unroll
      for (int gi = 0; gi < 16; ++gi) {
        const u16x8 cur = *(const u16x8*)&sbuf[cbuf][gi * 512 + lane * 8];
        u16x4 oc;
#pragma unroll
        for (int v = 0; v < 4; ++v) {
          const float wf = bf2f(cur[v]);
          const float wc = bf2f(cur[4 + v]);
          const float ef = __expf(-(wf + vfh * c));
          const float f  = 1.0f / (1.0f + ef);
          c = f * (c - wc) + wc;
          oc[v] = f2bf(c);
        }
        cw[(size_t)(wnd * 16 + gi) * 64] = oc;
      }
    }
    __syncthreads();   // next-window loads complete AND compute done
  }
  if (wave == 0) c_last[(size_t)b * HDIM + h] = c;
}

// ---------------- scan2: parallel r-gate + output ---------------------------
// 32768 blocks x 256 threads; block = (bhg, quarter q=blk&63); wave w of the
// block handles t4 = q*4 + w; lane = hl. All (bhg,t4) covered exactly once.
__global__ __launch_bounds__(256) void scan2_kernel(
    const u16x4* __restrict__ R,   // wr tiled
    const u16x4* __restrict__ Cc,  // c bf16 tiled
    const float* __restrict__ x,   // (B*S) x H f32
    const float* __restrict__ vr,
    float* __restrict__ h_out)     // (B*S) x H f32
{
  const int tid = threadIdx.x;
  const int blk = blockIdx.x;           // 0..32767
  const int bhg = blk >> 6;             // 0..511
  const int t4  = ((blk & 63) << 2) + (tid >> 6);  // 0..255
  const int hl  = tid & 63;
  const int b   = bhg >> 4;
  const int h   = ((bhg & 15) << 6) + hl;

  const size_t idx = ((size_t)bhg * 256 + t4) * 64 + hl;
  const u16x4 r4 = R[idx];
  const u16x4 c4 = Cc[idx];
  // clamp the prev-c address so a speculated load can't go below the buffer
  const size_t idxp = (t4 == 0) ? idx : idx - 64;
  const float cprev = (t4 == 0) ? 0.0f : bf2f(Cc[idxp][3]);
  const float vrh = vr[h];
  const float SC = 1.7320508075688772f; // sqrt(3)

  const float* px = x + ((size_t)b * SDIM + t4 * 4) * HDIM + h;
  float* ph = h_out + ((size_t)b * SDIM + t4 * 4) * HDIM + h;

#pragma unroll
  for (int v = 0; v < 4; ++v) {
    const float cp = (v == 0) ? cprev : bf2f(c4[v - 1]);
    const float er = __expf(-(bf2f(r4[v]) + vrh * cp));
    const float rr = 1.0f / (1.0f + er);
    const float xs = px[(size_t)v * HDIM] * SC;
    ph[(size_t)v * HDIM] = rr * (bf2f(c4[v]) - xs) + xs;
  }
}

extern "C" void kernel_launch(void* const* d_in, const int* in_sizes, int n_in,
                              void* d_out, int out_size, void* d_ws, size_t ws_size,
                              hipStream_t stream) {
  const float* x  = (const float*)d_in[0];
  const float* w  = (const float*)d_in[1];
  const float* b  = (const float*)d_in[2];
  const float* vf = (const float*)d_in[3];
  const float* vr = (const float*)d_in[4];

  float* out    = (float*)d_out;
  float* h_out  = out;                       // 33554432 f32
  float* c_last = out + (size_t)33554432;    // 32768 f32

  // workspace: xb[64MB] (later aliased by Cc) | wb[6MB] | PW[128MB] | R[64MB]
  char* ws = (char*)d_ws;
  u16*   xb = (u16*)ws;
  u16*   wb = (u16*)(ws + 67108864);
  u16x4* PW = (u16x4*)(ws + 73400320);
  u16x4* R  = (u16x4*)(ws + 73400320 + 134217728);
  u16x4* Cc = (u16x4*)ws;                    // aliases xb (dead after gemm)

  cast_kernel<<<4096, 256, 0, stream>>>(x, xb, 8388608);
  cast_kernel<<<1024, 256, 0, stream>>>(w, wb, 786432);
  gemm_kernel<<<(MT / 128) * (NT / 128), 256, 0, stream>>>(xb, wb, b, PW, R);
  scan1_kernel<<<512, 256, 0, stream>>>((const u16*)PW, vf, Cc, c_last);
  scan2_kernel<<<32768, 256, 0, stream>>>(R, Cc, x, vr, h_out);
}